// Round 1
// baseline (392.608 us; speedup 1.0000x reference)
//
#include <hip/hip_runtime.h>

#define NC 2048  // combined rows: [0,1024) = left, [1024,2048) = right
#define NPAIR 1048576

// ---------------- K1: xej = e.mean(axis=1), both sides ----------------
__global__ void k_xej(const float* __restrict__ el, const float* __restrict__ er,
                      float* __restrict__ xej) {
    int t = threadIdx.x;
    int c = blockIdx.x * 8 + (t >> 5);   // combined row
    int d = t & 31;
    const float* e = (c < 1024) ? el : er;
    int n = c & 1023;
    float s = 0.f;
    for (int k = 0; k < 32; ++k) s += e[n * 1024 + k * 32 + d];
    xej[c * 32 + d] = s * (1.f / 32.f);
}

// ---------------- K2: weight prep (transposes, concat, fold 0.5 into A1) ----------------
__global__ void k_wprep(const float* __restrict__ Wc1, const float* __restrict__ Wn1, const float* __restrict__ We1,
                        const float* __restrict__ Wc2, const float* __restrict__ Wn2, const float* __restrict__ We2,
                        const float* __restrict__ Wc3, const float* __restrict__ Wn3, const float* __restrict__ We3,
                        const float* __restrict__ A1,  const float* __restrict__ A2,
                        float* __restrict__ WT1, float* __restrict__ WT2, float* __restrict__ WT3,
                        float* __restrict__ A1t, float* __restrict__ A2t) {
    int i = blockIdx.x * 256 + threadIdx.x;
    if (i < 20480) {                       // WT1: (160 x 128), K-major
        int d = i >> 7, o = i & 127;
        WT1[i] = (d < 64) ? Wc1[o * 64 + d] : (d < 128) ? Wn1[o * 64 + (d - 64)] : We1[o * 32 + (d - 128)];
    } else if (i < 57344) {                // WT2: (288 x 128)
        int j = i - 20480; int d = j >> 7, o = j & 127;
        WT2[j] = (d < 128) ? Wc2[o * 128 + d] : (d < 256) ? Wn2[o * 128 + (d - 128)] : We2[o * 32 + (d - 256)];
    } else if (i < 75776) {                // WT3: (288 x 64)
        int j = i - 57344; int d = j >> 6, o = j & 63;
        WT3[j] = (d < 128) ? Wc3[o * 128 + d] : (d < 256) ? Wn3[o * 128 + (d - 128)] : We3[o * 32 + (d - 256)];
    } else if (i < 83968) {                // A1t: (64 x 128), 0.5 folded in
        int j = i - 75776; int d = j >> 7, o = j & 127;
        A1t[j] = 0.5f * A1[o * 64 + d];
    } else if (i < 92160) {                // A2t: (128 x 64)
        int j = i - 83968; int k = j >> 6, o = j & 63;
        A2t[j] = A2[o * 128 + k];
    }
}

// ---------------- K3: gather -> build concat input, column-major CT (K x 2048) ----------------
template<int NIN>
__global__ void k_gather(const float* __restrict__ xl, const float* __restrict__ xr,
                         const int* __restrict__ ijl, const int* __restrict__ ijr,
                         const float* __restrict__ xej, float* __restrict__ CT) {
    int t = threadIdx.x;
    int d = t & (NIN - 1);
    int cc0 = t / NIN;
    int c0 = blockIdx.x * 32;
    const int CPP = 256 / NIN;            // columns per pass
    for (int p = 0; p < 32; p += CPP) {
        int c = c0 + p + cc0;
        int n = c & 1023;
        bool left = (c < 1024);
        const float* xp = left ? xl : xr;
        const int*  ijp = left ? ijl : ijr;
        // x part
        CT[d * NC + c] = xp[n * NIN + d];
        // neighbor-mean part
        float s = 0.f;
        for (int k = 0; k < 32; ++k) {
            int nh = ijp[n * 32 + k];
            s += xp[nh * NIN + d];
        }
        CT[(NIN + d) * NC + c] = s * (1.f / 32.f);
        // edge-mean part
        if (d < 32) CT[(2 * NIN + d) * NC + c] = xej[c * 32 + d];
    }
}

// ---------------- K4/K5: small GEMM, wave-uniform scalar weights ----------------
// out(n,o) = act( sum_d in(n,d) * WT(d,o) );  one wave per (64 rows x 32 outs)
template<int K, int NOUT, bool ROWMAJOR, bool RELU>
__global__ void k_gemm(const float* __restrict__ in, const float* __restrict__ WT,
                       float* __restrict__ out) {
    int lane = threadIdx.x;
    int n  = blockIdx.x * 64 + lane;
    int o0 = blockIdx.y * 32;
    float acc[32];
#pragma unroll
    for (int i = 0; i < 32; ++i) acc[i] = 0.f;
    for (int d = 0; d < K; ++d) {
        float xd = ROWMAJOR ? in[n * K + d] : in[d * NC + n];
        const float* w = WT + d * NOUT + o0;   // wave-uniform -> s_load
#pragma unroll
        for (int i = 0; i < 32; ++i) acc[i] = fmaf(w[i], xd, acc[i]);
    }
#pragma unroll
    for (int i = 0; i < 32; ++i)
        out[n * NOUT + o0 + i] = RELU ? fmaxf(acc[i], 0.f) : acc[i];
}

// ---------------- K6: dense over 1M pairs ----------------
// h1 = relu(Ul_i + Ur_j); h2 = relu(A2 h1); out = relu(A3 h2)
__global__ void k_dense(const float* __restrict__ U, const float* __restrict__ A2t,
                        const float* __restrict__ A3, float* __restrict__ out) {
    __shared__ float ur[64 * 129];        // odd stride: 2-way banks (free)
    int t = threadIdx.x;
    int j0 = blockIdx.x * 64;             // right tile
    int i0 = blockIdx.y * 4;              // left tile
    for (int idx = t; idx < 64 * 128; idx += 256) {
        int r = idx >> 7, k = idx & 127;
        ur[r * 129 + k] = U[(1024 + j0 + r) * 128 + k];
    }
    __syncthreads();
    int ti = t >> 6, tj = t & 63;
    int irow = __builtin_amdgcn_readfirstlane(i0 + ti);   // wave-uniform -> scalar loads
    const float* ulrow = U + irow * 128;
    const float* urrow = ur + tj * 129;
    float acc[64];
#pragma unroll
    for (int o = 0; o < 64; ++o) acc[o] = 0.f;
    for (int k = 0; k < 128; ++k) {
        float h = fmaxf(ulrow[k] + urrow[k], 0.f);
        const float* w = A2t + k * 64;    // uniform -> SGPRs, v_fmac v,s,v
#pragma unroll
        for (int o = 0; o < 64; ++o) acc[o] = fmaf(w[o], h, acc[o]);
    }
    float r0 = 0.f, r1 = 0.f;
#pragma unroll
    for (int o = 0; o < 64; ++o) {
        float h2 = fmaxf(acc[o], 0.f);
        r0 = fmaf(A3[o], h2, r0);
        r1 = fmaf(A3[64 + o], h2, r1);
    }
    int p = (i0 + ti) * 1024 + j0 + tj;   // coalesced 256B stores per wave
    out[p] = fmaxf(r0, 0.f);
    out[NPAIR + p] = fmaxf(r1, 0.f);
}

extern "C" void kernel_launch(void* const* d_in, const int* in_sizes, int n_in,
                              void* d_out, int out_size, void* d_ws, size_t ws_size,
                              hipStream_t stream) {
    const float* xnr = (const float*)d_in[0];
    const float* xer = (const float*)d_in[1];
    const int*   ijr = (const int*)  d_in[2];
    const float* xnl = (const float*)d_in[3];
    const float* xel = (const float*)d_in[4];
    const int*   ijl = (const int*)  d_in[5];
    const float* Wc1 = (const float*)d_in[6];
    const float* Wn1 = (const float*)d_in[7];
    const float* We1 = (const float*)d_in[8];
    const float* Wc2 = (const float*)d_in[9];
    const float* Wn2 = (const float*)d_in[10];
    const float* We2 = (const float*)d_in[11];
    const float* Wc3 = (const float*)d_in[12];
    const float* Wn3 = (const float*)d_in[13];
    const float* We3 = (const float*)d_in[14];
    const float* A1  = (const float*)d_in[15];
    const float* A2  = (const float*)d_in[16];
    const float* A3  = (const float*)d_in[17];
    float* out = (float*)d_out;

    float* ws  = (float*)d_ws;
    float* xej = ws;                  // 2048*32      = 65536
    float* WT1 = xej + 65536;         // 160*128      = 20480
    float* WT2 = WT1 + 20480;         // 288*128      = 36864
    float* WT3 = WT2 + 36864;         // 288*64       = 18432
    float* A1t = WT3 + 18432;         // 64*128       = 8192
    float* A2t = A1t + 8192;          // 128*64       = 8192
    float* CT  = A2t + 8192;          // 288*2048     = 589824 (reused per layer)
    float* X1  = CT  + 589824;        // 2048*128     = 262144
    float* X2  = X1  + 262144;        // 2048*128     = 262144
    float* X3  = X2  + 262144;        // 2048*64      = 131072
    float* U   = X3  + 131072;        // 2048*128     = 262144

    k_xej<<<256, 256, 0, stream>>>(xel, xer, xej);
    k_wprep<<<360, 256, 0, stream>>>(Wc1, Wn1, We1, Wc2, Wn2, We2, Wc3, Wn3, We3, A1, A2,
                                     WT1, WT2, WT3, A1t, A2t);
    // layer 1: NIN=64 -> 128
    k_gather<64><<<64, 256, 0, stream>>>(xnl, xnr, ijl, ijr, xej, CT);
    k_gemm<160, 128, false, true><<<dim3(32, 4), 64, 0, stream>>>(CT, WT1, X1);
    // layer 2: 128 -> 128
    k_gather<128><<<64, 256, 0, stream>>>(X1, X1 + 1024 * 128, ijl, ijr, xej, CT);
    k_gemm<288, 128, false, true><<<dim3(32, 4), 64, 0, stream>>>(CT, WT2, X2);
    // layer 3: 128 -> 64
    k_gather<128><<<64, 256, 0, stream>>>(X2, X2 + 1024 * 128, ijl, ijr, xej, CT);
    k_gemm<288, 64, false, true><<<dim3(32, 2), 64, 0, stream>>>(CT, WT3, X3);
    // U = 0.5 * A1 @ x3 (no relu)
    k_gemm<64, 128, true, false><<<dim3(32, 4), 64, 0, stream>>>(X3, A1t, U);
    // dense over all pairs
    k_dense<<<dim3(16, 256), 256, 0, stream>>>(U, A2t, A3, out);
}

// Round 2
// 141.265 us; speedup vs baseline: 2.7792x; 2.7792x over previous
//
#include <hip/hip_runtime.h>
#include <hip/hip_bf16.h>

#define NC 2048       // combined rows: [0,1024) = left, [1024,2048) = right
#define NPAIR 1048576

typedef __attribute__((ext_vector_type(8))) short bf16x8;
typedef __attribute__((ext_vector_type(4))) float f32x4;

__device__ inline short f2bf(float f) {
    __hip_bfloat16 h = __float2bfloat16(f);
    return __builtin_bit_cast(short, h);
}

// ---------------- K1: xej = e.mean(axis=1), both sides ----------------
__global__ void k_xej(const float* __restrict__ el, const float* __restrict__ er,
                      float* __restrict__ xej) {
    int t = threadIdx.x;
    int c = blockIdx.x * 8 + (t >> 5);
    int d = t & 31;
    const float* e = (c < 1024) ? el : er;
    int n = c & 1023;
    float s = 0.f;
#pragma unroll
    for (int k = 0; k < 32; ++k) s += e[n * 1024 + k * 32 + d];
    xej[c * 32 + d] = s * (1.f / 32.f);
}

// ---------------- K2: weight prep ----------------
// WT1/WT2/WT3 K-major f32; A1t (0.5 folded); Bprep = A2 as pre-swizzled bf16 B-frags
__global__ void k_wprep(const float* __restrict__ Wc1, const float* __restrict__ Wn1, const float* __restrict__ We1,
                        const float* __restrict__ Wc2, const float* __restrict__ Wn2, const float* __restrict__ We2,
                        const float* __restrict__ Wc3, const float* __restrict__ Wn3, const float* __restrict__ We3,
                        const float* __restrict__ A1,  const float* __restrict__ A2,
                        float* __restrict__ WT1, float* __restrict__ WT2, float* __restrict__ WT3,
                        float* __restrict__ A1t, short* __restrict__ Bprep) {
    int i = blockIdx.x * 256 + threadIdx.x;
    if (i < 20480) {                       // WT1: (160 x 128)
        int d = i >> 7, o = i & 127;
        WT1[i] = (d < 64) ? Wc1[o * 64 + d] : (d < 128) ? Wn1[o * 64 + (d - 64)] : We1[o * 32 + (d - 128)];
    } else if (i < 57344) {                // WT2: (288 x 128)
        int j = i - 20480; int d = j >> 7, o = j & 127;
        WT2[j] = (d < 128) ? Wc2[o * 128 + d] : (d < 256) ? Wn2[o * 128 + (d - 128)] : We2[o * 32 + (d - 256)];
    } else if (i < 75776) {                // WT3: (288 x 64)
        int j = i - 57344; int d = j >> 6, o = j & 63;
        WT3[j] = (d < 128) ? Wc3[o * 128 + d] : (d < 256) ? Wn3[o * 128 + (d - 128)] : We3[o * 32 + (d - 256)];
    } else if (i < 83968) {                // A1t: (64 x 128), 0.5 folded in
        int j = i - 75776; int d = j >> 7, o = j & 127;
        A1t[j] = 0.5f * A1[o * 64 + d];
    } else if (i < 92160) {                // Bprep: 16 frags x 64 lanes x 8 bf16
        int j = i - 83968;
        int ktnt = j >> 9, l = (j >> 3) & 63, e = j & 7;
        int kt = ktnt >> 2, nt = ktnt & 3;
        int k = kt * 32 + (l >> 4) * 8 + e;
        int o = nt * 16 + (l & 15);
        Bprep[j] = f2bf(A2[o * 128 + k]);
    }
}

// ---------------- K3: gather -> concat input, column-major CT (K x 2048) ----------------
template<int NIN>
__global__ void k_gather(const float* __restrict__ xl, const float* __restrict__ xr,
                         const int* __restrict__ ijl, const int* __restrict__ ijr,
                         const float* __restrict__ xej, float* __restrict__ CT) {
    int t = threadIdx.x;
    int d = t & (NIN - 1);
    int c = blockIdx.x * (256 / NIN) + t / NIN;   // c wave-uniform
    int n = c & 1023;
    bool left = (c < 1024);
    const float* xp = left ? xl : xr;
    const int*  ijp = left ? ijl : ijr;
    int nb = __builtin_amdgcn_readfirstlane(n);
    CT[d * NC + c] = xp[n * NIN + d];
    float s = 0.f;
#pragma unroll
    for (int k = 0; k < 32; ++k) {
        int nh = ijp[nb * 32 + k];                // s_load (uniform)
        s += xp[nh * NIN + d];                    // coalesced vector load
    }
    CT[(NIN + d) * NC + c] = s * (1.f / 32.f);
    if (d < 32) CT[(2 * NIN + d) * NC + c] = xej[c * 32 + d];
}

// ---------------- K4: small GEMM, wave-uniform scalar weights, 8 outs/thread ----------------
template<int K, int NOUT, bool ROWMAJOR, bool RELU>
__global__ void k_gemm(const float* __restrict__ in, const float* __restrict__ WT,
                       float* __restrict__ out) {
    int n  = blockIdx.x * 64 + threadIdx.x;
    int o0 = blockIdx.y * 8;
    float acc[8];
#pragma unroll
    for (int i = 0; i < 8; ++i) acc[i] = 0.f;
    for (int d = 0; d < K; ++d) {
        float xd = ROWMAJOR ? in[n * K + d] : in[d * NC + n];
        const float* w = WT + d * NOUT + o0;      // wave-uniform -> s_load
#pragma unroll
        for (int i = 0; i < 8; ++i) acc[i] = fmaf(w[i], xd, acc[i]);
    }
#pragma unroll
    for (int i = 0; i < 8; ++i)
        out[n * NOUT + o0 + i] = RELU ? fmaxf(acc[i], 0.f) : acc[i];
}

// ---------------- K5: dense over 1M pairs via bf16 MFMA ----------------
// h1 = relu(Ul_i + Ur_j) built per A-frag; h2 = A2@h1 via 16x16x32 MFMA; out = relu(A3@relu(h2))
__global__ __launch_bounds__(256) void k_dense(const float* __restrict__ U,
                                               const short* __restrict__ Bprep,
                                               const float* __restrict__ A3,
                                               float* __restrict__ out) {
    __shared__ float ur[64 * 132];           // stride 132: 2-way bank aliasing only (free)
    int t = threadIdx.x;
    int lane = t & 63;
    int w = t >> 6;
    int j0 = blockIdx.x * 64;
    int i  = blockIdx.y * 4 + w;

    // stage Ur tile (64 rows x 128), float4, coalesced
    for (int idx = t; idx < 2048; idx += 256) {
        int r = idx >> 5, k4 = (idx & 31) << 2;
        *(f32x4*)&ur[r * 132 + k4] = *(const f32x4*)&U[(1024 + j0 + r) * 128 + k4];
    }

    int col = lane & 15, g = lane >> 4;

    // B-frags: pre-swizzled, one b128 load each, live in regs for whole kernel
    bf16x8 bf[4][4];
#pragma unroll
    for (int kt = 0; kt < 4; ++kt)
#pragma unroll
        for (int nt = 0; nt < 4; ++nt)
            bf[kt][nt] = *(const bf16x8*)&Bprep[((kt * 4 + nt) * 64 + lane) * 8];

    // Ul slice for this lane: k = kt*32 + g*8 + e
    float ulv[4][8];
#pragma unroll
    for (int kt = 0; kt < 4; ++kt) {
        const float* p = U + i * 128 + kt * 32 + g * 8;
        f32x4 a = *(const f32x4*)p, b = *(const f32x4*)(p + 4);
#pragma unroll
        for (int e = 0; e < 4; ++e) { ulv[kt][e] = a[e]; ulv[kt][4 + e] = b[e]; }
    }

    // A3 slice: a3v[c][nt] = A3[c*64 + nt*16 + col]
    float a3v[2][4];
#pragma unroll
    for (int c = 0; c < 2; ++c)
#pragma unroll
        for (int nt = 0; nt < 4; ++nt)
            a3v[c][nt] = A3[c * 64 + nt * 16 + col];

    __syncthreads();

    for (int jg = 0; jg < 4; ++jg) {
        // A-frags: pair = col (A-operand M index = lane&15), k-slice = g*8
        bf16x8 af[4];
        const float* urow = ur + (jg * 16 + col) * 132 + g * 8;
#pragma unroll
        for (int kt = 0; kt < 4; ++kt) {
            f32x4 u0 = *(const f32x4*)(urow + kt * 32);
            f32x4 u1 = *(const f32x4*)(urow + kt * 32 + 4);
#pragma unroll
            for (int e = 0; e < 4; ++e) {
                af[kt][e]     = f2bf(fmaxf(ulv[kt][e]     + u0[e], 0.f));
                af[kt][4 + e] = f2bf(fmaxf(ulv[kt][4 + e] + u1[e], 0.f));
            }
        }
        f32x4 acc[4] = {{0,0,0,0},{0,0,0,0},{0,0,0,0},{0,0,0,0}};
#pragma unroll
        for (int nt = 0; nt < 4; ++nt)
#pragma unroll
            for (int kt = 0; kt < 4; ++kt)
                acc[nt] = __builtin_amdgcn_mfma_f32_16x16x32_bf16(af[kt], bf[kt][nt], acc[nt], 0, 0, 0);

        // epilogue: D layout col=lane&15 (=h2 dim within tile), row=(lane>>4)*4+r (=pair)
        f32x4 s0 = {0,0,0,0}, s1 = {0,0,0,0};
#pragma unroll
        for (int nt = 0; nt < 4; ++nt)
#pragma unroll
            for (int r = 0; r < 4; ++r) {
                float h = fmaxf(acc[nt][r], 0.f);
                s0[r] = fmaf(a3v[0][nt], h, s0[r]);
                s1[r] = fmaf(a3v[1][nt], h, s1[r]);
            }
#pragma unroll
        for (int dlt = 1; dlt < 16; dlt <<= 1) {
#pragma unroll
            for (int r = 0; r < 4; ++r) {
                s0[r] += __shfl_xor(s0[r], dlt, 64);
                s1[r] += __shfl_xor(s1[r], dlt, 64);
            }
        }
        if (col == 0) {
            int p = i * 1024 + j0 + jg * 16 + g * 4;
            f32x4 o0 = {fmaxf(s0[0],0.f), fmaxf(s0[1],0.f), fmaxf(s0[2],0.f), fmaxf(s0[3],0.f)};
            f32x4 o1 = {fmaxf(s1[0],0.f), fmaxf(s1[1],0.f), fmaxf(s1[2],0.f), fmaxf(s1[3],0.f)};
            *(f32x4*)&out[p] = o0;
            *(f32x4*)&out[NPAIR + p] = o1;
        }
    }
}

extern "C" void kernel_launch(void* const* d_in, const int* in_sizes, int n_in,
                              void* d_out, int out_size, void* d_ws, size_t ws_size,
                              hipStream_t stream) {
    const float* xnr = (const float*)d_in[0];
    const float* xer = (const float*)d_in[1];
    const int*   ijr = (const int*)  d_in[2];
    const float* xnl = (const float*)d_in[3];
    const float* xel = (const float*)d_in[4];
    const int*   ijl = (const int*)  d_in[5];
    const float* Wc1 = (const float*)d_in[6];
    const float* Wn1 = (const float*)d_in[7];
    const float* We1 = (const float*)d_in[8];
    const float* Wc2 = (const float*)d_in[9];
    const float* Wn2 = (const float*)d_in[10];
    const float* We2 = (const float*)d_in[11];
    const float* Wc3 = (const float*)d_in[12];
    const float* Wn3 = (const float*)d_in[13];
    const float* We3 = (const float*)d_in[14];
    const float* A1  = (const float*)d_in[15];
    const float* A2  = (const float*)d_in[16];
    const float* A3  = (const float*)d_in[17];
    float* out = (float*)d_out;

    float* ws  = (float*)d_ws;
    float* xej = ws;                  // 2048*32      = 65536
    float* WT1 = xej + 65536;         // 160*128      = 20480
    float* WT2 = WT1 + 20480;         // 288*128      = 36864
    float* WT3 = WT2 + 36864;         // 288*64       = 18432
    float* A1t = WT3 + 18432;         // 64*128       = 8192
    short* Bpp = (short*)(A1t + 8192);// 8192 shorts  = 4096 floats
    float* CT  = A1t + 8192 + 4096;   // 288*2048     = 589824 (reused per layer)
    float* X1  = CT  + 589824;        // 2048*128     = 262144
    float* X2  = X1  + 262144;        // 2048*128     = 262144
    float* X3  = X2  + 262144;        // 2048*64      = 131072
    float* U   = X3  + 131072;        // 2048*128     = 262144

    k_xej<<<256, 256, 0, stream>>>(xel, xer, xej);
    k_wprep<<<360, 256, 0, stream>>>(Wc1, Wn1, We1, Wc2, Wn2, We2, Wc3, Wn3, We3, A1, A2,
                                     WT1, WT2, WT3, A1t, Bpp);
    // layer 1: NIN=64 -> 128
    k_gather<64><<<512, 256, 0, stream>>>(xnl, xnr, ijl, ijr, xej, CT);
    k_gemm<160, 128, false, true><<<dim3(32, 16), 64, 0, stream>>>(CT, WT1, X1);
    // layer 2: 128 -> 128
    k_gather<128><<<1024, 256, 0, stream>>>(X1, X1 + 1024 * 128, ijl, ijr, xej, CT);
    k_gemm<288, 128, false, true><<<dim3(32, 16), 64, 0, stream>>>(CT, WT2, X2);
    // layer 3: 128 -> 64
    k_gather<128><<<1024, 256, 0, stream>>>(X2, X2 + 1024 * 128, ijl, ijr, xej, CT);
    k_gemm<288, 64, false, true><<<dim3(32, 8), 64, 0, stream>>>(CT, WT3, X3);
    // U = 0.5 * A1 @ x3 (no relu)
    k_gemm<64, 128, true, false><<<dim3(32, 16), 64, 0, stream>>>(X3, A1t, U);
    // dense over all pairs, MFMA
    k_dense<<<dim3(16, 256), 256, 0, stream>>>(U, Bpp, A3, out);
}

// Round 3
// 118.207 us; speedup vs baseline: 3.3214x; 1.1951x over previous
//
#include <hip/hip_runtime.h>
#include <hip/hip_bf16.h>

#define NC 2048       // combined rows: [0,1024) = left, [1024,2048) = right
#define NPAIR 1048576

typedef __attribute__((ext_vector_type(8))) short bf16x8;
typedef __attribute__((ext_vector_type(4))) float f32x4;
typedef __attribute__((ext_vector_type(4))) unsigned int u32x4;

__device__ inline short f2bf(float f) {
    __hip_bfloat16 h = __float2bfloat16(f);
    return __builtin_bit_cast(short, h);
}
__device__ inline unsigned cvt_pk(float a, float b) {   // dst.lo=bf16(a), dst.hi=bf16(b), RNE
    unsigned r;
    asm("v_cvt_pk_bf16_f32 %0, %1, %2" : "=v"(r) : "v"(a), "v"(b));
    return r;
}

// ---------------- K1: xej = e.mean(axis=1), both sides ----------------
__global__ void k_xej(const float* __restrict__ el, const float* __restrict__ er,
                      float* __restrict__ xej) {
    int t = threadIdx.x;
    int c = blockIdx.x * 8 + (t >> 5);
    int d = t & 31;
    const float* e = (c < 1024) ? el : er;
    int n = c & 1023;
    float s = 0.f;
#pragma unroll
    for (int k = 0; k < 32; ++k) s += e[n * 1024 + k * 32 + d];
    xej[c * 32 + d] = s * (1.f / 32.f);
}

// ---------------- K2: weight prep ----------------
// WT* K-major f32; A1t (0.5 folded); Bpp = A2 frags (permuted rows) + A3 hi/lo frags, bf16
__global__ void k_wprep(const float* __restrict__ Wc1, const float* __restrict__ Wn1, const float* __restrict__ We1,
                        const float* __restrict__ Wc2, const float* __restrict__ Wn2, const float* __restrict__ We2,
                        const float* __restrict__ Wc3, const float* __restrict__ Wn3, const float* __restrict__ We3,
                        const float* __restrict__ A1,  const float* __restrict__ A2,  const float* __restrict__ A3,
                        float* __restrict__ WT1, float* __restrict__ WT2, float* __restrict__ WT3,
                        float* __restrict__ A1t, short* __restrict__ Bpp) {
    int i = blockIdx.x * 256 + threadIdx.x;
    if (i < 20480) {                       // WT1: (160 x 128)
        int d = i >> 7, o = i & 127;
        WT1[i] = (d < 64) ? Wc1[o * 64 + d] : (d < 128) ? Wn1[o * 64 + (d - 64)] : We1[o * 32 + (d - 128)];
    } else if (i < 57344) {                // WT2: (288 x 128)
        int j = i - 20480; int d = j >> 7, o = j & 127;
        WT2[j] = (d < 128) ? Wc2[o * 128 + d] : (d < 256) ? Wn2[o * 128 + (d - 128)] : We2[o * 32 + (d - 256)];
    } else if (i < 75776) {                // WT3: (288 x 64)
        int j = i - 57344; int d = j >> 6, o = j & 63;
        WT3[j] = (d < 128) ? Wc3[o * 128 + d] : (d < 256) ? Wn3[o * 128 + (d - 128)] : We3[o * 32 + (d - 256)];
    } else if (i < 83968) {                // A1t: (64 x 128), 0.5 folded in
        int j = i - 75776; int d = j >> 7, o = j & 127;
        A1t[j] = 0.5f * A1[o * 64 + d];
    } else if (i < 92160) {                // A2 frags: 16 x 64 lanes x 8, permuted h2 rows
        int j = i - 83968;
        int ktnt = j >> 9, l = (j >> 3) & 63, e = j & 7;
        int kt = ktnt >> 2, nt = ktnt & 3;
        int m = l & 15;
        int o = (nt >> 1) * 32 + (m >> 2) * 8 + (nt & 1) * 4 + (m & 3);   // permuted row
        int k = kt * 32 + (l >> 4) * 8 + e;
        Bpp[j] = f2bf(A2[o * 128 + k]);
    } else if (i < 94208) {                // A3 frags: (c,p=hi/lo) x 64 lanes x 8
        int j = i - 92160;
        int cp = j >> 9, l = (j >> 3) & 63, e = j & 7;
        int c = cp >> 1, p = cp & 1;
        int m = l & 15;
        int h2 = c * 32 + (l >> 4) * 8 + e;
        float v = (m < 2) ? A3[m * 64 + h2] : 0.f;
        short hi = f2bf(v);
        float vh = __bfloat162float(__builtin_bit_cast(__hip_bfloat16, hi));
        Bpp[8192 + j] = p ? f2bf(v - vh) : hi;
    }
}

// ---------------- K3: gather -> concat input, column-major CT (K x 2048) ----------------
template<int NIN>
__global__ void k_gather(const float* __restrict__ xl, const float* __restrict__ xr,
                         const int* __restrict__ ijl, const int* __restrict__ ijr,
                         const float* __restrict__ xej, float* __restrict__ CT) {
    int t = threadIdx.x;
    int d = t & (NIN - 1);
    int c = blockIdx.x * (256 / NIN) + t / NIN;   // c wave-uniform
    int n = c & 1023;
    bool left = (c < 1024);
    const float* xp = left ? xl : xr;
    const int*  ijp = left ? ijl : ijr;
    int nb = __builtin_amdgcn_readfirstlane(n);
    CT[d * NC + c] = xp[n * NIN + d];
    float s = 0.f;
#pragma unroll
    for (int k = 0; k < 32; ++k) {
        int nh = ijp[nb * 32 + k];                // s_load (uniform)
        s += xp[nh * NIN + d];                    // coalesced vector load
    }
    CT[(NIN + d) * NC + c] = s * (1.f / 32.f);
    if (d < 32) CT[(2 * NIN + d) * NC + c] = xej[c * 32 + d];
}

// ---------------- K4: split-K small GEMM partials ----------------
// P[kb][n][o] = sum_{d in part kb} in[d][n] * WT[d][o]; in column-major stride NC
template<int KB, int NOUT>
__global__ void k_gemm_part(const float* __restrict__ in, const float* __restrict__ WT,
                            float* __restrict__ P) {
    int n  = blockIdx.x * 64 + threadIdx.x;
    int o0 = blockIdx.y * 8;
    int d0 = blockIdx.z * KB;
    float acc[8];
#pragma unroll
    for (int i = 0; i < 8; ++i) acc[i] = 0.f;
#pragma unroll 4
    for (int dd = 0; dd < KB; ++dd) {
        int d = d0 + dd;
        float xd = in[d * NC + n];
        const float* w = WT + d * NOUT + o0;      // wave-uniform -> s_load
#pragma unroll
        for (int i = 0; i < 8; ++i) acc[i] = fmaf(w[i], xd, acc[i]);
    }
    float* p = P + blockIdx.z * (NC * NOUT) + n * NOUT + o0;
#pragma unroll
    for (int i = 0; i < 8; ++i) p[i] = acc[i];
}

// ---------------- K5: reduce partials (+relu, optional transpose) ----------------
template<int TOTAL, int PARTS, bool RELU, bool TRANS, int NOUT>
__global__ void k_reduce(const float* __restrict__ P, float* __restrict__ X) {
    if (!TRANS) {
        int i4 = (blockIdx.x * 256 + threadIdx.x) * 4;
        f32x4 s = *(const f32x4*)&P[i4];
#pragma unroll
        for (int p = 1; p < PARTS; ++p) {
            f32x4 q = *(const f32x4*)&P[p * TOTAL + i4];
#pragma unroll
            for (int e = 0; e < 4; ++e) s[e] += q[e];
        }
        if (RELU) {
#pragma unroll
            for (int e = 0; e < 4; ++e) s[e] = fmaxf(s[e], 0.f);
        }
        *(f32x4*)&X[i4] = s;
    } else {
        int i = blockIdx.x * 256 + threadIdx.x;
        float s = P[i];
#pragma unroll
        for (int p = 1; p < PARTS; ++p) s += P[p * TOTAL + i];
        if (RELU) s = fmaxf(s, 0.f);
        X[(i % NOUT) * NC + i / NOUT] = s;        // transpose to column-major
    }
}

// ---------------- K6: dense over 1M pairs, double-MFMA (no shuffles) ----------------
// h1 = relu(Ul_i + Ur_j) as B-frag; h2t = mfma(A2frag, h1) -> pair=col;
// permuted h2 rows make acc1 regs == B-frag of second mfma; out = relu(mfma(A3hi/lo, relu(h2)))
__global__ __launch_bounds__(256) void k_dense(const float* __restrict__ U,
                                               const short* __restrict__ Bpp,
                                               float* __restrict__ out) {
    __shared__ float ur[64 * 132];           // stride 132: minor conflicts (measured ~128cyc/wave)
    int t = threadIdx.x;
    int lane = t & 63;
    int w = t >> 6;
    int j0 = blockIdx.x * 64;
    int i  = blockIdx.y * 4 + w;
    int col = lane & 15, g = lane >> 4;

    // stage Ur tile (64 rows x 128), float4, coalesced
    for (int idx = t; idx < 2048; idx += 256) {
        int r = idx >> 5, k4 = (idx & 31) << 2;
        *(f32x4*)&ur[r * 132 + k4] = *(const f32x4*)&U[(1024 + j0 + r) * 128 + k4];
    }

    // A2 frags (A-operand, permuted rows): 16 x b128, in regs all kernel
    bf16x8 a2f[4][4];
#pragma unroll
    for (int kt = 0; kt < 4; ++kt)
#pragma unroll
        for (int nt = 0; nt < 4; ++nt)
            a2f[kt][nt] = *(const bf16x8*)&Bpp[((kt * 4 + nt) * 64 + lane) * 8];

    // A3 frags, hi/lo split
    bf16x8 a3f[2][2];
#pragma unroll
    for (int c = 0; c < 2; ++c)
#pragma unroll
        for (int p = 0; p < 2; ++p)
            a3f[c][p] = *(const bf16x8*)&Bpp[8192 + ((c * 2 + p) * 64 + lane) * 8];

    // Ul slice for this wave's row i: k = kt*32 + g*8 + e
    float ulv[4][8];
#pragma unroll
    for (int kt = 0; kt < 4; ++kt) {
        const float* p = U + i * 128 + kt * 32 + g * 8;
        f32x4 a = *(const f32x4*)p, b = *(const f32x4*)(p + 4);
#pragma unroll
        for (int e = 0; e < 4; ++e) { ulv[kt][e] = a[e]; ulv[kt][4 + e] = b[e]; }
    }

    __syncthreads();

    for (int jg = 0; jg < 4; ++jg) {
        const float* urow = ur + (jg * 16 + col) * 132 + g * 8;
        // h1 B-frag: n=pair=col, k=kt*32+g*8+e
        bf16x8 h1f[4];
#pragma unroll
        for (int kt = 0; kt < 4; ++kt) {
            f32x4 u0 = *(const f32x4*)(urow + kt * 32);
            f32x4 u1 = *(const f32x4*)(urow + kt * 32 + 4);
            u32x4 pw;
            pw[0] = cvt_pk(fmaxf(ulv[kt][0] + u0[0], 0.f), fmaxf(ulv[kt][1] + u0[1], 0.f));
            pw[1] = cvt_pk(fmaxf(ulv[kt][2] + u0[2], 0.f), fmaxf(ulv[kt][3] + u0[3], 0.f));
            pw[2] = cvt_pk(fmaxf(ulv[kt][4] + u1[0], 0.f), fmaxf(ulv[kt][5] + u1[1], 0.f));
            pw[3] = cvt_pk(fmaxf(ulv[kt][6] + u1[2], 0.f), fmaxf(ulv[kt][7] + u1[3], 0.f));
            h1f[kt] = __builtin_bit_cast(bf16x8, pw);
        }
        // h2t = A2 @ h1 : D col = pair, D row-group regs match next B-frag under row perm
        f32x4 acc1[4] = {{0,0,0,0},{0,0,0,0},{0,0,0,0},{0,0,0,0}};
#pragma unroll
        for (int nt = 0; nt < 4; ++nt)
#pragma unroll
            for (int kt = 0; kt < 4; ++kt)
                acc1[nt] = __builtin_amdgcn_mfma_f32_16x16x32_bf16(a2f[kt][nt], h1f[kt], acc1[nt], 0, 0, 0);

        // out = (A3hi + A3lo) @ relu(h2)
        f32x4 accO = {0, 0, 0, 0};
#pragma unroll
        for (int c = 0; c < 2; ++c) {
            u32x4 pw;
            pw[0] = cvt_pk(fmaxf(acc1[2 * c][0], 0.f), fmaxf(acc1[2 * c][1], 0.f));
            pw[1] = cvt_pk(fmaxf(acc1[2 * c][2], 0.f), fmaxf(acc1[2 * c][3], 0.f));
            pw[2] = cvt_pk(fmaxf(acc1[2 * c + 1][0], 0.f), fmaxf(acc1[2 * c + 1][1], 0.f));
            pw[3] = cvt_pk(fmaxf(acc1[2 * c + 1][2], 0.f), fmaxf(acc1[2 * c + 1][3], 0.f));
            bf16x8 hb = __builtin_bit_cast(bf16x8, pw);
            accO = __builtin_amdgcn_mfma_f32_16x16x32_bf16(a3f[c][0], hb, accO, 0, 0, 0);
            accO = __builtin_amdgcn_mfma_f32_16x16x32_bf16(a3f[c][1], hb, accO, 0, 0, 0);
        }
        // D: col=pair, row=g*4+r -> rows 0,1 live on lanes 0..15
        if (lane < 16) {
            int p = i * 1024 + j0 + jg * 16 + col;
            out[p]         = fmaxf(accO[0], 0.f);
            out[NPAIR + p] = fmaxf(accO[1], 0.f);
        }
    }
}

extern "C" void kernel_launch(void* const* d_in, const int* in_sizes, int n_in,
                              void* d_out, int out_size, void* d_ws, size_t ws_size,
                              hipStream_t stream) {
    const float* xnr = (const float*)d_in[0];
    const float* xer = (const float*)d_in[1];
    const int*   ijr = (const int*)  d_in[2];
    const float* xnl = (const float*)d_in[3];
    const float* xel = (const float*)d_in[4];
    const int*   ijl = (const int*)  d_in[5];
    const float* Wc1 = (const float*)d_in[6];
    const float* Wn1 = (const float*)d_in[7];
    const float* We1 = (const float*)d_in[8];
    const float* Wc2 = (const float*)d_in[9];
    const float* Wn2 = (const float*)d_in[10];
    const float* We2 = (const float*)d_in[11];
    const float* Wc3 = (const float*)d_in[12];
    const float* Wn3 = (const float*)d_in[13];
    const float* We3 = (const float*)d_in[14];
    const float* A1  = (const float*)d_in[15];
    const float* A2  = (const float*)d_in[16];
    const float* A3  = (const float*)d_in[17];
    float* out = (float*)d_out;

    float* ws  = (float*)d_ws;
    float* xej = ws;                   // 65536
    float* WT1 = xej + 65536;          // 20480
    float* WT2 = WT1 + 20480;          // 36864
    float* WT3 = WT2 + 36864;          // 18432
    float* A1t = WT3 + 18432;          // 8192
    short* Bpp = (short*)(A1t + 8192); // 10240 shorts = 5120 floats
    float* CT  = A1t + 8192 + 5120;    // 589824
    float* XA  = CT + 589824;          // 262144 (activations, also X3T)
    float* P   = XA + 262144;          // 524288 (partials; chunk0 doubles as U)
    float* U   = P;

    k_xej<<<256, 256, 0, stream>>>(xel, xer, xej);
    k_wprep<<<368, 256, 0, stream>>>(Wc1, Wn1, We1, Wc2, Wn2, We2, Wc3, Wn3, We3, A1, A2, A3,
                                     WT1, WT2, WT3, A1t, Bpp);
    // layer 1: 64 -> 128
    k_gather<64><<<512, 256, 0, stream>>>(xnl, xnr, ijl, ijr, xej, CT);
    k_gemm_part<80, 128><<<dim3(32, 16, 2), 64, 0, stream>>>(CT, WT1, P);
    k_reduce<262144, 2, true, false, 128><<<256, 256, 0, stream>>>(P, XA);
    // layer 2: 128 -> 128
    k_gather<128><<<1024, 256, 0, stream>>>(XA, XA + 1024 * 128, ijl, ijr, xej, CT);
    k_gemm_part<144, 128><<<dim3(32, 16, 2), 64, 0, stream>>>(CT, WT2, P);
    k_reduce<262144, 2, true, false, 128><<<256, 256, 0, stream>>>(P, XA);
    // layer 3: 128 -> 64 (reduce transposes -> X3T column-major in XA)
    k_gather<128><<<1024, 256, 0, stream>>>(XA, XA + 1024 * 128, ijl, ijr, xej, CT);
    k_gemm_part<72, 64><<<dim3(32, 8, 4), 64, 0, stream>>>(CT, WT3, P);
    k_reduce<131072, 4, true, true, 64><<<512, 256, 0, stream>>>(P, XA);
    // U = 0.5 * A1 @ x3 (column-major X3T input, no relu); U lands in P chunk0
    k_gemm_part<32, 128><<<dim3(32, 16, 2), 64, 0, stream>>>(XA, A1t, P);
    k_reduce<262144, 2, false, false, 128><<<256, 256, 0, stream>>>(P, U);
    // dense over all pairs
    k_dense<<<dim3(16, 256), 256, 0, stream>>>(U, Bpp, out);
}